// Round 2
// baseline (2369.357 us; speedup 1.0000x reference)
//
#include <hip/hip_runtime.h>
#include <math.h>

// GatedAttention: B=32, C=512, T=1024, fp32.
// Stage 1 (qkv_kernel): q/k/v[b,t,d] = gate[b,d,t] * (sum_c x[b,c,t]*W[d,c] + b[d])
// Stage 2 (energy_kernel): E[b,c,d] = SCALE * sum_t Q[b,t,c]*K[b,t,d]
// Stage 3 (softmax_kernel): row softmax over d
// Stage 4 (out_kernel): out[b,c,t] = sum_d A[b,c,d]*V[b,t,d]
//
// Workspace is sized adaptively: per-batch need = 3*T*C*4 (Q,K,V) + C*C*4 (E)
// = 7 MB. We pick the largest batch-chunk that fits ws_size and loop chunks.
// (Round-0 postmortem: assumed 224 MB of d_ws unconditionally — if ws_size is
// smaller that overruns the buffer and aborts the container.)

#define B_ 32
#define C_ 512
#define T_ 1024
#define SCALE_ 0.04419417382415922f  // 1/sqrt(512)

__global__ __launch_bounds__(256) void qkv_kernel(
    const float* __restrict__ x,
    const float* __restrict__ gq, const float* __restrict__ gk, const float* __restrict__ gv,
    const float* __restrict__ Wq, const float* __restrict__ bq,
    const float* __restrict__ Wk, const float* __restrict__ bk,
    const float* __restrict__ Wv, const float* __restrict__ bv,
    float* __restrict__ Q, float* __restrict__ Km, float* __restrict__ Vm,
    int b_off)
{
    const int tid = threadIdx.x;
    const int bl = blockIdx.z;          // local batch (workspace index)
    const int bg = b_off + bl;          // global batch (input index)
    const int t0 = blockIdx.x * 64;
    const int d0 = blockIdx.y * 64;

    __shared__ float sX[32][65];   // [c][t]
    __shared__ float sWq[32][65];  // [c][d]  (transposed on load)
    __shared__ float sWk[32][65];
    __shared__ float sWv[32][65];

    const int dq = tid & 15;   // d quad -> lanes consecutive in d (coalesced stores)
    const int tq = tid >> 4;   // t quad

    float aq[4][4] = {{0.f}}, ak[4][4] = {{0.f}}, av[4][4] = {{0.f}};

    for (int c0 = 0; c0 < C_; c0 += 32) {
        #pragma unroll
        for (int i = 0; i < 8; ++i) {
            int idx = tid + i * 256;
            int cc = idx >> 6, tt = idx & 63;
            sX[cc][tt] = x[(size_t)(bg * C_ + c0 + cc) * T_ + t0 + tt];
        }
        #pragma unroll
        for (int i = 0; i < 8; ++i) {
            int idx = tid + i * 256;
            int cc = idx & 31, dd = idx >> 5;
            sWq[cc][dd] = Wq[(size_t)(d0 + dd) * C_ + c0 + cc];
            sWk[cc][dd] = Wk[(size_t)(d0 + dd) * C_ + c0 + cc];
            sWv[cc][dd] = Wv[(size_t)(d0 + dd) * C_ + c0 + cc];
        }
        __syncthreads();

        #pragma unroll 4
        for (int cc = 0; cc < 32; ++cc) {
            float xs[4], wq4[4], wk4[4], wv4[4];
            #pragma unroll
            for (int i = 0; i < 4; ++i) xs[i] = sX[cc][tq * 4 + i];
            #pragma unroll
            for (int j = 0; j < 4; ++j) {
                wq4[j] = sWq[cc][dq * 4 + j];
                wk4[j] = sWk[cc][dq * 4 + j];
                wv4[j] = sWv[cc][dq * 4 + j];
            }
            #pragma unroll
            for (int i = 0; i < 4; ++i)
                #pragma unroll
                for (int j = 0; j < 4; ++j) {
                    aq[i][j] = fmaf(xs[i], wq4[j], aq[i][j]);
                    ak[i][j] = fmaf(xs[i], wk4[j], ak[i][j]);
                    av[i][j] = fmaf(xs[i], wv4[j], av[i][j]);
                }
        }
        __syncthreads();
    }

    #pragma unroll
    for (int i = 0; i < 4; ++i) {
        int t = t0 + tq * 4 + i;
        #pragma unroll
        for (int j = 0; j < 4; ++j) {
            int d = d0 + dq * 4 + j;
            size_t gidx = (size_t)(bg * C_ + d) * T_ + t;   // gate[b,d,t]
            size_t oidx = (size_t)(bl * T_ + t) * C_ + d;   // [b,t,d] local
            Q[oidx]  = gq[gidx] * (aq[i][j] + bq[d]);
            Km[oidx] = gk[gidx] * (ak[i][j] + bk[d]);
            Vm[oidx] = gv[gidx] * (av[i][j] + bv[d]);
        }
    }
}

__global__ __launch_bounds__(256) void energy_kernel(
    const float* __restrict__ Q, const float* __restrict__ Km, float* __restrict__ E)
{
    const int tid = threadIdx.x;
    const int bl = blockIdx.z;
    const int c0 = blockIdx.y * 64;
    const int d0 = blockIdx.x * 64;

    __shared__ float sQ[32][65];  // [t][c]
    __shared__ float sK[32][65];  // [t][d]

    const int dq = tid & 15;
    const int cq = tid >> 4;

    float acc[4][4] = {{0.f}};

    for (int t0 = 0; t0 < T_; t0 += 32) {
        #pragma unroll
        for (int i = 0; i < 8; ++i) {
            int idx = tid + i * 256;
            int cc = idx & 63, tt = idx >> 6;
            sQ[tt][cc] = Q[(size_t)(bl * T_ + t0 + tt) * C_ + c0 + cc];
            sK[tt][cc] = Km[(size_t)(bl * T_ + t0 + tt) * C_ + d0 + cc];
        }
        __syncthreads();

        #pragma unroll 4
        for (int tt = 0; tt < 32; ++tt) {
            float qs[4], ks[4];
            #pragma unroll
            for (int i = 0; i < 4; ++i) qs[i] = sQ[tt][cq * 4 + i];
            #pragma unroll
            for (int j = 0; j < 4; ++j) ks[j] = sK[tt][dq * 4 + j];
            #pragma unroll
            for (int i = 0; i < 4; ++i)
                #pragma unroll
                for (int j = 0; j < 4; ++j)
                    acc[i][j] = fmaf(qs[i], ks[j], acc[i][j]);
        }
        __syncthreads();
    }

    #pragma unroll
    for (int i = 0; i < 4; ++i) {
        int c = c0 + cq * 4 + i;
        #pragma unroll
        for (int j = 0; j < 4; ++j) {
            int d = d0 + dq * 4 + j;
            E[(size_t)(bl * C_ + c) * C_ + d] = acc[i][j] * SCALE_;
        }
    }
}

__global__ __launch_bounds__(256) void softmax_kernel(float* __restrict__ E)
{
    const int row = blockIdx.x;  // (chunk*C) rows of length C
    float* p = E + (size_t)row * C_;
    const int tid = threadIdx.x;

    float v0 = p[tid], v1 = p[tid + 256];
    float m = fmaxf(v0, v1);
    #pragma unroll
    for (int off = 32; off > 0; off >>= 1)
        m = fmaxf(m, __shfl_down(m, off, 64));

    __shared__ float sm[4];
    if ((tid & 63) == 0) sm[tid >> 6] = m;
    __syncthreads();
    float M = fmaxf(fmaxf(sm[0], sm[1]), fmaxf(sm[2], sm[3]));

    float e0 = expf(v0 - M), e1 = expf(v1 - M);
    float s = e0 + e1;
    #pragma unroll
    for (int off = 32; off > 0; off >>= 1)
        s += __shfl_down(s, off, 64);

    __shared__ float ss[4];
    if ((tid & 63) == 0) ss[tid >> 6] = s;
    __syncthreads();
    float inv = 1.0f / (ss[0] + ss[1] + ss[2] + ss[3]);

    p[tid] = e0 * inv;
    p[tid + 256] = e1 * inv;
}

__global__ __launch_bounds__(256) void out_kernel(
    const float* __restrict__ A, const float* __restrict__ Vm, float* __restrict__ out,
    int b_off)
{
    const int tid = threadIdx.x;
    const int bl = blockIdx.z;
    const int bg = b_off + bl;
    const int c0 = blockIdx.y * 64;
    const int t0 = blockIdx.x * 64;

    __shared__ float sA[64][33];  // [c][d]
    __shared__ float sV[64][33];  // [t][d]

    const int tq = tid & 15;   // lanes consecutive in t (coalesced out stores)
    const int cq = tid >> 4;

    float acc[4][4] = {{0.f}};  // [c][t]

    for (int d0 = 0; d0 < C_; d0 += 32) {
        #pragma unroll
        for (int i = 0; i < 8; ++i) {
            int idx = tid + i * 256;
            int dd = idx & 31, rr = idx >> 5;
            sA[rr][dd] = A[(size_t)(bl * C_ + c0 + rr) * C_ + d0 + dd];
            sV[rr][dd] = Vm[(size_t)(bl * T_ + t0 + rr) * C_ + d0 + dd];
        }
        __syncthreads();

        #pragma unroll 4
        for (int dd = 0; dd < 32; ++dd) {
            float as[4], vs[4];
            #pragma unroll
            for (int i = 0; i < 4; ++i) as[i] = sA[cq * 4 + i][dd];
            #pragma unroll
            for (int j = 0; j < 4; ++j) vs[j] = sV[tq * 4 + j][dd];
            #pragma unroll
            for (int i = 0; i < 4; ++i)
                #pragma unroll
                for (int j = 0; j < 4; ++j)
                    acc[i][j] = fmaf(as[i], vs[j], acc[i][j]);
        }
        __syncthreads();
    }

    #pragma unroll
    for (int i = 0; i < 4; ++i) {
        int c = c0 + cq * 4 + i;
        #pragma unroll
        for (int j = 0; j < 4; ++j) {
            int t = t0 + tq * 4 + j;
            out[(size_t)(bg * C_ + c) * T_ + t] = acc[i][j];
        }
    }
}

extern "C" void kernel_launch(void* const* d_in, const int* in_sizes, int n_in,
                              void* d_out, int out_size, void* d_ws, size_t ws_size,
                              hipStream_t stream) {
    const float* x  = (const float*)d_in[0];
    const float* gq = (const float*)d_in[1];
    const float* gk = (const float*)d_in[2];
    const float* gv = (const float*)d_in[3];
    const float* Wq = (const float*)d_in[4];
    const float* bq = (const float*)d_in[5];
    const float* Wk = (const float*)d_in[6];
    const float* bk = (const float*)d_in[7];
    const float* Wv = (const float*)d_in[8];
    const float* bv = (const float*)d_in[9];
    float* out = (float*)d_out;

    // Per-batch workspace: Q,K,V = T*C floats each, E = C*C floats.
    const size_t perQ = (size_t)T_ * C_;            // elements
    const size_t perE = (size_t)C_ * C_;
    const size_t perBatchBytes = (3 * perQ + perE) * sizeof(float);  // 7 MB

    int bc = 1;
    for (int cand = B_; cand >= 1; cand >>= 1) {
        if ((size_t)cand * perBatchBytes <= ws_size) { bc = cand; break; }
    }

    float* Q  = (float*)d_ws;
    float* Km = Q  + (size_t)bc * perQ;
    float* Vm = Km + (size_t)bc * perQ;
    float* E  = Vm + (size_t)bc * perQ;

    dim3 blk(256);
    for (int b_off = 0; b_off < B_; b_off += bc) {
        qkv_kernel<<<dim3(T_ / 64, C_ / 64, bc), blk, 0, stream>>>(
            x, gq, gk, gv, Wq, bq, Wk, bk, Wv, bv, Q, Km, Vm, b_off);
        energy_kernel<<<dim3(C_ / 64, C_ / 64, bc), blk, 0, stream>>>(Q, Km, E);
        softmax_kernel<<<dim3(bc * C_), blk, 0, stream>>>(E);
        out_kernel<<<dim3(T_ / 64, C_ / 64, bc), blk, 0, stream>>>(E, Vm, out, b_off);
    }
}

// Round 3
// 671.072 us; speedup vs baseline: 3.5307x; 3.5307x over previous
//
#include <hip/hip_runtime.h>
#include <math.h>

// GatedAttention B=32, C=512, T=1024, fp32 in/out.
// Split-bf16 (hi/lo) MFMA implementation:
//   T0: transpose+split x -> xThi/xTlo[b,t,c] (bf16), transpose gv -> gvT[b,t,d] (fp32)
//   W:  split Wq/Wk/Wv -> hi/lo bf16 planes [d][c]
//   G1: qT[d,t] = gq[d,t]*(Wq . xT + bq)      (M=d,N=t,K=c)  -> Qhi/Qlo [d][t]
//       kT[d,t] likewise                                      -> Khi/Klo [d][t]
//       v[t,d]  = gvT[t,d]*(xT . Wv^T + bv)   (M=t,N=d,K=c)  -> Vhi/Vlo [t][d]
//   G2: E[c,d] = SCALE * Q[c,:] . K[d,:]      (K=t=1024), fp32
//   S:  row softmax over d, split -> Ahi/Alo [c][d]
//   G3: out[c,t] = attn[c,:] . V[t,:]^T       (K=d=512), fp32 direct to d_out
// All GEMMs are NT form: A[m][k], B[n][k], both k-contiguous; 3 MFMA passes
// (Ah*Bh + Ah*Bl + Al*Bh) approximate fp32 to ~2^-16 relative.

#define B_ 32
#define C_ 512
#define T_ 1024
#define TC_ ((size_t)524288)   // T*C == C*T
#define CC_ ((size_t)262144)   // C*C
#define SCALE_ 0.04419417382415922f  // 1/sqrt(512)

typedef short bf16x8 __attribute__((ext_vector_type(8)));
typedef float f32x4 __attribute__((ext_vector_type(4)));

__device__ __forceinline__ unsigned short f2b(float f) {
    unsigned int u = __float_as_uint(f);
    u += 0x7fff + ((u >> 16) & 1);          // round-to-nearest-even
    return (unsigned short)(u >> 16);
}
__device__ __forceinline__ float b2f(unsigned short h) {
    return __uint_as_float(((unsigned int)h) << 16);
}

#define GLDS(gp, lp) __builtin_amdgcn_global_load_lds( \
    (const __attribute__((address_space(1))) unsigned int*)(const void*)(gp), \
    (__attribute__((address_space(3))) unsigned int*)(void*)(lp), 16, 0, 0)

// ---------------- generic split-bf16 NT GEMM ----------------
// C[m][n] = sum_k A[m][k]*B[n][k], 128x128 tile, BK=32, 256 threads (4 waves),
// each wave a 64x64 quadrant as 4x4 grid of 16x16x32 MFMA tiles.
// EP 0: val=gate[m*N+n]*(acc+bias[m]), split-store -> Chi/Clo
// EP 1: val=gate[m*N+n]*(acc+bias[n]), split-store -> Chi/Clo
// EP 2: Cf[m*N+n] = acc*SCALE_
// EP 3: Cf[m*N+n] = acc
template<int M, int N, int K, int EP>
__global__ __launch_bounds__(256, 2) void gemm_nt(
    const unsigned short* __restrict__ Ahi, const unsigned short* __restrict__ Alo, size_t sA,
    const unsigned short* __restrict__ Bhi, const unsigned short* __restrict__ Blo, size_t sB,
    float* __restrict__ Cf, size_t sCf,
    unsigned short* __restrict__ Chi, unsigned short* __restrict__ Clo, size_t sC,
    const float* __restrict__ gate, size_t sG,
    const float* __restrict__ bias)
{
    __shared__ __attribute__((aligned(16))) unsigned short sAh[128 * 32];
    __shared__ __attribute__((aligned(16))) unsigned short sAl[128 * 32];
    __shared__ __attribute__((aligned(16))) unsigned short sBh[128 * 32];
    __shared__ __attribute__((aligned(16))) unsigned short sBl[128 * 32];

    const int tid  = threadIdx.x;
    const int lane = tid & 63;
    const int wave = tid >> 6;
    const int bz   = blockIdx.z;
    const int m0   = blockIdx.y * 128;
    const int n0   = blockIdx.x * 128;

    const unsigned short* pAh = Ahi + (size_t)bz * sA;
    const unsigned short* pAl = Alo + (size_t)bz * sA;
    const unsigned short* pBh = Bhi + (size_t)bz * sB;
    const unsigned short* pBl = Blo + (size_t)bz * sB;

    // staging: wave stages rows [wave*32, wave*32+32) of both tiles, 2 issues of
    // 16 rows each; lane -> row srow+lane/4, k-chunk (lane&3)*8. LDS dest is
    // wave-uniform base + lane*16 (global_load_lds semantics).
    const int srow = wave * 32;
    const int lr   = lane >> 2;
    const int lk   = (lane & 3) * 8;
    const size_t gA0 = (size_t)(m0 + srow + lr) * K + lk;
    const size_t gA1 = (size_t)(m0 + srow + 16 + lr) * K + lk;
    const size_t gB0 = (size_t)(n0 + srow + lr) * K + lk;
    const size_t gB1 = (size_t)(n0 + srow + 16 + lr) * K + lk;
    unsigned short* lds0 = nullptr;  (void)lds0;

    // fragment coords
    const int wm = (wave & 1) * 64;
    const int wn = (wave >> 1) * 64;
    const int fr = lane & 15;
    const int fk = (lane >> 4) * 8;

    f32x4 acc[4][4] = {};

    for (int k0 = 0; k0 < K; k0 += 32) {
        GLDS(pAh + gA0 + k0, &sAh[srow * 32]);
        GLDS(pAh + gA1 + k0, &sAh[(srow + 16) * 32]);
        GLDS(pAl + gA0 + k0, &sAl[srow * 32]);
        GLDS(pAl + gA1 + k0, &sAl[(srow + 16) * 32]);
        GLDS(pBh + gB0 + k0, &sBh[srow * 32]);
        GLDS(pBh + gB1 + k0, &sBh[(srow + 16) * 32]);
        GLDS(pBl + gB0 + k0, &sBl[srow * 32]);
        GLDS(pBl + gB1 + k0, &sBl[(srow + 16) * 32]);
        __syncthreads();   // drains vmcnt, publishes LDS

        bf16x8 aH[4], aL[4], bH[4], bL[4];
        #pragma unroll
        for (int i = 0; i < 4; ++i) {
            int ar = (wm + i * 16 + fr) * 32 + fk;
            int br = (wn + i * 16 + fr) * 32 + fk;
            aH[i] = *(const bf16x8*)(const void*)&sAh[ar];
            aL[i] = *(const bf16x8*)(const void*)&sAl[ar];
            bH[i] = *(const bf16x8*)(const void*)&sBh[br];
            bL[i] = *(const bf16x8*)(const void*)&sBl[br];
        }
        #pragma unroll
        for (int mi = 0; mi < 4; ++mi)
            #pragma unroll
            for (int ni = 0; ni < 4; ++ni) {
                acc[mi][ni] = __builtin_amdgcn_mfma_f32_16x16x32_bf16(aL[mi], bH[ni], acc[mi][ni], 0, 0, 0);
                acc[mi][ni] = __builtin_amdgcn_mfma_f32_16x16x32_bf16(aH[mi], bL[ni], acc[mi][ni], 0, 0, 0);
                acc[mi][ni] = __builtin_amdgcn_mfma_f32_16x16x32_bf16(aH[mi], bH[ni], acc[mi][ni], 0, 0, 0);
            }
        __syncthreads();   // protect LDS before next staging
    }

    // epilogue: C/D layout col=lane&15 (n), row=(lane>>4)*4+reg (m)
    #pragma unroll
    for (int mi = 0; mi < 4; ++mi) {
        #pragma unroll
        for (int r = 0; r < 4; ++r) {
            int m = m0 + wm + mi * 16 + (lane >> 4) * 4 + r;
            #pragma unroll
            for (int ni = 0; ni < 4; ++ni) {
                int n = n0 + wn + ni * 16 + fr;
                float v = acc[mi][ni][r];
                size_t idx = (size_t)m * N + n;
                if (EP == 0 || EP == 1) {
                    float g = gate[(size_t)bz * sG + idx];
                    float val = g * (v + bias[EP == 0 ? m : n]);
                    unsigned short h = f2b(val);
                    Chi[(size_t)bz * sC + idx] = h;
                    Clo[(size_t)bz * sC + idx] = f2b(val - b2f(h));
                } else if (EP == 2) {
                    Cf[(size_t)bz * sCf + idx] = v * SCALE_;
                } else {
                    Cf[(size_t)bz * sCf + idx] = v;
                }
            }
        }
    }
}

// ---------------- transpose + split ----------------
// job 0: x[b,c,t] fp32 -> xThi/xTlo[bz,t,c] bf16
// job 1: gv[b,d,t] fp32 -> gvT[bz,t,d] fp32
__global__ __launch_bounds__(256) void transpose_split(
    const float* __restrict__ x, const float* __restrict__ gv,
    unsigned short* __restrict__ xThi, unsigned short* __restrict__ xTlo,
    float* __restrict__ gvT, int bc, int b_off)
{
    __shared__ float s[64][65];
    const int z = blockIdx.z;
    const int job = z / bc, bz = z % bc;
    const int t0 = blockIdx.x * 64, c0 = blockIdx.y * 64;
    const float* src = (job ? gv : x) + (size_t)(b_off + bz) * TC_;
    const int col = threadIdx.x & 63, rb = threadIdx.x >> 6;

    #pragma unroll
    for (int i = 0; i < 64; i += 4)
        s[i + rb][col] = src[(size_t)(c0 + i + rb) * T_ + t0 + col];
    __syncthreads();

    const size_t ob = (size_t)bz * TC_;
    #pragma unroll
    for (int i = 0; i < 64; i += 4) {
        int tr = i + rb;
        float v = s[col][tr];
        size_t o = ob + (size_t)(t0 + tr) * C_ + c0 + col;
        if (job == 0) {
            unsigned short h = f2b(v);
            xThi[o] = h;
            xTlo[o] = f2b(v - b2f(h));
        } else {
            gvT[o] = v;
        }
    }
}

__global__ __launch_bounds__(256) void split_mat(
    const float* __restrict__ W, unsigned short* __restrict__ hi,
    unsigned short* __restrict__ lo, int n)
{
    int i = blockIdx.x * 256 + threadIdx.x;
    if (i < n) {
        float v = W[i];
        unsigned short h = f2b(v);
        hi[i] = h;
        lo[i] = f2b(v - b2f(h));
    }
}

// row softmax over 512, then split-store attn to bf16 hi/lo
__global__ __launch_bounds__(256) void softmax_split(
    const float* __restrict__ E, unsigned short* __restrict__ Ahi,
    unsigned short* __restrict__ Alo)
{
    const int row = blockIdx.x;
    const float* p = E + (size_t)row * C_;
    const int tid = threadIdx.x;

    float v0 = p[tid], v1 = p[tid + 256];
    float m = fmaxf(v0, v1);
    #pragma unroll
    for (int off = 32; off > 0; off >>= 1)
        m = fmaxf(m, __shfl_down(m, off, 64));

    __shared__ float sm[4];
    if ((tid & 63) == 0) sm[tid >> 6] = m;
    __syncthreads();
    float M = fmaxf(fmaxf(sm[0], sm[1]), fmaxf(sm[2], sm[3]));

    float e0 = expf(v0 - M), e1 = expf(v1 - M);
    float s = e0 + e1;
    #pragma unroll
    for (int off = 32; off > 0; off >>= 1)
        s += __shfl_down(s, off, 64);

    __shared__ float ss[4];
    if ((tid & 63) == 0) ss[tid >> 6] = s;
    __syncthreads();
    float inv = 1.0f / (ss[0] + ss[1] + ss[2] + ss[3]);

    float a0 = e0 * inv, a1 = e1 * inv;
    size_t o = (size_t)row * C_ + tid;
    unsigned short h0 = f2b(a0);
    Ahi[o] = h0;  Alo[o] = f2b(a0 - b2f(h0));
    unsigned short h1 = f2b(a1);
    Ahi[o + 256] = h1;  Alo[o + 256] = f2b(a1 - b2f(h1));
}

extern "C" void kernel_launch(void* const* d_in, const int* in_sizes, int n_in,
                              void* d_out, int out_size, void* d_ws, size_t ws_size,
                              hipStream_t stream) {
    const float* x  = (const float*)d_in[0];
    const float* gq = (const float*)d_in[1];
    const float* gk = (const float*)d_in[2];
    const float* gv = (const float*)d_in[3];
    const float* Wq = (const float*)d_in[4];
    const float* bq = (const float*)d_in[5];
    const float* Wk = (const float*)d_in[6];
    const float* bk = (const float*)d_in[7];
    const float* Wv = (const float*)d_in[8];
    const float* bv = (const float*)d_in[9];
    float* out = (float*)d_out;

    // Workspace: W planes (batch-independent) + per-batch region.
    // per batch: xT hi/lo 2*TC*2 + gvT TC*4 + QKV hi/lo 6*TC*2 + E CC*4 + attn 2*CC*2
    const size_t wBytes = 6 * CC_ * 2;                                  // 3 MB
    const size_t perBatch = 2 * TC_ * 2 + TC_ * 4 + 6 * TC_ * 2
                          + CC_ * 4 + 2 * CC_ * 2;                       // 12 MB
    int bc = 1;
    for (int cand = B_; cand >= 1; cand >>= 1)
        if (wBytes + (size_t)cand * perBatch <= ws_size) { bc = cand; break; }

    char* p = (char*)d_ws;
    auto take = [&](size_t bytes) { char* r = p; p += bytes; return r; };
    unsigned short* Wqh = (unsigned short*)take(CC_ * 2);
    unsigned short* Wql = (unsigned short*)take(CC_ * 2);
    unsigned short* Wkh = (unsigned short*)take(CC_ * 2);
    unsigned short* Wkl = (unsigned short*)take(CC_ * 2);
    unsigned short* Wvh = (unsigned short*)take(CC_ * 2);
    unsigned short* Wvl = (unsigned short*)take(CC_ * 2);
    unsigned short* xThi = (unsigned short*)take((size_t)bc * TC_ * 2);
    unsigned short* xTlo = (unsigned short*)take((size_t)bc * TC_ * 2);
    float*          gvT  = (float*)take((size_t)bc * TC_ * 4);
    unsigned short* Qh = (unsigned short*)take((size_t)bc * TC_ * 2);
    unsigned short* Ql = (unsigned short*)take((size_t)bc * TC_ * 2);
    unsigned short* Kh = (unsigned short*)take((size_t)bc * TC_ * 2);
    unsigned short* Kl = (unsigned short*)take((size_t)bc * TC_ * 2);
    unsigned short* Vh = (unsigned short*)take((size_t)bc * TC_ * 2);
    unsigned short* Vl = (unsigned short*)take((size_t)bc * TC_ * 2);
    float*          E  = (float*)take((size_t)bc * CC_ * 4);
    unsigned short* Ah = (unsigned short*)take((size_t)bc * CC_ * 2);
    unsigned short* Al = (unsigned short*)take((size_t)bc * CC_ * 2);

    dim3 blk(256);
    split_mat<<<(int)(CC_ / 256), blk, 0, stream>>>(Wq, Wqh, Wql, (int)CC_);
    split_mat<<<(int)(CC_ / 256), blk, 0, stream>>>(Wk, Wkh, Wkl, (int)CC_);
    split_mat<<<(int)(CC_ / 256), blk, 0, stream>>>(Wv, Wvh, Wvl, (int)CC_);

    for (int b_off = 0; b_off < B_; b_off += bc) {
        transpose_split<<<dim3(T_ / 64, C_ / 64, 2 * bc), blk, 0, stream>>>(
            x, gv, xThi, xTlo, gvT, bc, b_off);

        // qT[d,t], kT[d,t]: M=512(d), N=1024(t), K=512(c)
        gemm_nt<512, 1024, 512, 0><<<dim3(8, 4, bc), blk, 0, stream>>>(
            Wqh, Wql, 0, xThi, xTlo, TC_, nullptr, 0, Qh, Ql, TC_,
            gq + (size_t)b_off * TC_, TC_, bq);
        gemm_nt<512, 1024, 512, 0><<<dim3(8, 4, bc), blk, 0, stream>>>(
            Wkh, Wkl, 0, xThi, xTlo, TC_, nullptr, 0, Kh, Kl, TC_,
            gk + (size_t)b_off * TC_, TC_, bk);
        // v[t,d]: M=1024(t), N=512(d), K=512(c); gate gvT local-batch
        gemm_nt<1024, 512, 512, 1><<<dim3(4, 8, bc), blk, 0, stream>>>(
            xThi, xTlo, TC_, Wvh, Wvl, 0, nullptr, 0, Vh, Vl, TC_,
            gvT, TC_, bv);
        // E[c,d]: M=512, N=512, K=1024(t)
        gemm_nt<512, 512, 1024, 2><<<dim3(4, 4, bc), blk, 0, stream>>>(
            Qh, Ql, TC_, Kh, Kl, TC_, E, CC_, nullptr, nullptr, 0, nullptr, 0, nullptr);
        softmax_split<<<dim3(bc * C_), blk, 0, stream>>>(E, Ah, Al);
        // out[c,t]: M=512(c), N=1024(t), K=512(d)
        gemm_nt<512, 1024, 512, 3><<<dim3(8, 4, bc), blk, 0, stream>>>(
            Ah, Al, CC_, Vh, Vl, TC_, out + (size_t)b_off * TC_, TC_,
            nullptr, nullptr, 0, nullptr, 0, nullptr);
    }
}